// Round 1
// baseline (989.590 us; speedup 1.0000x reference)
//
#include <hip/hip_runtime.h>

#define NNODES 100000
#define NREL 8
#define EMB 64
#define RN (NREL * NNODES)          // 800000 rows of h
#define KDIM (NREL * EMB)           // 512 reduction dim for fused GEMM

// ---------------------------------------------------------------------------
// K1: degree count per (relation,target) row
// ---------------------------------------------------------------------------
__global__ void k_degree(const int* __restrict__ rows, int* __restrict__ deg, int E) {
    int e = blockIdx.x * blockDim.x + threadIdx.x;
    if (e < E) atomicAdd(&deg[rows[e]], 1);
}

// ---------------------------------------------------------------------------
// K2: scatter normalized messages into H[n, r*64 + k]  (node-major layout)
// one 64-lane group per edge; lane = embedding index
// ---------------------------------------------------------------------------
__global__ void k_scatter(const int* __restrict__ rows, const int* __restrict__ cols,
                          const int* __restrict__ deg, const float* __restrict__ x,
                          float* __restrict__ H, int E) {
    int e = blockIdx.x * (blockDim.x >> 6) + (threadIdx.x >> 6);
    if (e >= E) return;
    int row = rows[e];
    int c   = cols[e];
    int r   = row / NNODES;              // compiler magic-mul
    int t   = row - r * NNODES;
    float inv = 1.0f / (float)deg[row];  // deg >= 1 for any row that has an edge
    int f = threadIdx.x & 63;
    atomicAdd(&H[(size_t)t * KDIM + r * EMB + f],
              inv * x[(size_t)c * EMB + f]);
}

// ---------------------------------------------------------------------------
// K3: out = relu(H[N,512] @ Wflat[512,64]); Wflat is `weights` viewed flat
// thread per output element; wave = one node (H loads broadcast, W coalesced)
// ---------------------------------------------------------------------------
__global__ void k_gemm(const float* __restrict__ H, const float* __restrict__ W,
                       float* __restrict__ out) {
    int tid = blockIdx.x * blockDim.x + threadIdx.x;   // n*64 + f
    int n = tid >> 6;
    int f = tid & 63;
    const float* h = H + (size_t)n * KDIM;
    float acc = 0.f;
#pragma unroll 4
    for (int j0 = 0; j0 < KDIM; j0 += 8) {
        float4 h0 = *reinterpret_cast<const float4*>(h + j0);
        float4 h1 = *reinterpret_cast<const float4*>(h + j0 + 4);
        acc = fmaf(h0.x, W[(j0 + 0) * EMB + f], acc);
        acc = fmaf(h0.y, W[(j0 + 1) * EMB + f], acc);
        acc = fmaf(h0.z, W[(j0 + 2) * EMB + f], acc);
        acc = fmaf(h0.w, W[(j0 + 3) * EMB + f], acc);
        acc = fmaf(h1.x, W[(j0 + 4) * EMB + f], acc);
        acc = fmaf(h1.y, W[(j0 + 5) * EMB + f], acc);
        acc = fmaf(h1.z, W[(j0 + 6) * EMB + f], acc);
        acc = fmaf(h1.w, W[(j0 + 7) * EMB + f], acc);
    }
    out[tid] = fmaxf(acc, 0.f);
}

// ---------------------------------------------------------------------------
extern "C" void kernel_launch(void* const* d_in, const int* in_sizes, int n_in,
                              void* d_out, int out_size, void* d_ws, size_t ws_size,
                              hipStream_t stream) {
    const float* x    = (const float*)d_in[0];
    const float* w    = (const float*)d_in[1];
    const int*   rows = (const int*)d_in[2];   // JAX x64-disabled -> int32
    const int*   cols = (const int*)d_in[3];
    float*       out  = (float*)d_out;
    int E = in_sizes[2];

    int*   deg = (int*)d_ws;
    float* H   = (float*)((char*)d_ws + (size_t)RN * sizeof(int));  // 3.2MB offset

    size_t zero_bytes = (size_t)RN * sizeof(int) + (size_t)NNODES * KDIM * sizeof(float);
    hipMemsetAsync(d_ws, 0, zero_bytes, stream);

    k_degree<<<(E + 255) / 256, 256, 0, stream>>>(rows, deg, E);
    k_scatter<<<(E + 3) / 4, 256, 0, stream>>>(rows, cols, deg, x, H, E);
    k_gemm<<<(NNODES * EMB) / 256, 256, 0, stream>>>(H, w, out);
}

// Round 2
// 346.184 us; speedup vs baseline: 2.8586x; 2.8586x over previous
//
#include <hip/hip_runtime.h>

#define NNODES 100000
#define NREL 8
#define EMB 64
#define RN (NREL * NNODES)          // 800000 rows of h
#define KDIM (NREL * EMB)           // 512 reduction dim for fused GEMM

typedef __attribute__((ext_vector_type(8))) short bf16x8;   // 8 bf16 (4 VGPRs)
typedef __attribute__((ext_vector_type(4))) float f32x4;

__device__ inline unsigned short f2bf(float f) {
    union { float f; unsigned u; } v; v.f = f;
    return (unsigned short)((v.u + 0x7FFFu + ((v.u >> 16) & 1u)) >> 16);  // RNE
}

// ---------------------------------------------------------------------------
// K1: degree count per (relation,target) row
// ---------------------------------------------------------------------------
__global__ void k_degree(const int* __restrict__ rows, int* __restrict__ deg, int E) {
    int e = blockIdx.x * blockDim.x + threadIdx.x;
    if (e < E) atomicAdd(&deg[rows[e]], 1);
}

// ---------------------------------------------------------------------------
// K2: scatter normalized messages into H[n, r*64 + k]  (node-major layout)
// one 64-lane group per edge; lane = embedding index
// ---------------------------------------------------------------------------
__global__ void k_scatter(const int* __restrict__ rows, const int* __restrict__ cols,
                          const int* __restrict__ deg, const float* __restrict__ x,
                          float* __restrict__ H, int E) {
    int e = blockIdx.x * (blockDim.x >> 6) + (threadIdx.x >> 6);
    if (e >= E) return;
    int row = rows[e];
    int c   = cols[e];
    int r   = row / NNODES;              // compiler magic-mul
    int t   = row - r * NNODES;
    float inv = 1.0f / (float)deg[row];  // deg >= 1 for any row that has an edge
    int f = threadIdx.x & 63;
    atomicAdd(&H[(size_t)t * KDIM + r * EMB + f],
              inv * x[(size_t)c * EMB + f]);
}

// ---------------------------------------------------------------------------
// K3: out = relu(H[N,512] @ Wflat[512,64]) via bf16 MFMA 16x16x32.
// Block = 512 thr (8 waves); wave computes 16 rows x 64 cols (4 C-tiles).
// W staged once/block into LDS as bf16 [col][k], XOR-swizzled per 8-k block
// so B-fragment ds_read_b128 is ~2-way conflict max.
// ---------------------------------------------------------------------------
__global__ __launch_bounds__(512, 4) void k_gemm_mfma(const float* __restrict__ H,
                                                      const float* __restrict__ W,
                                                      float* __restrict__ out) {
    __shared__ unsigned short WT[EMB * KDIM];   // [col][k] swizzled, 64 KiB exactly
    const int tid = threadIdx.x;

    // stage W (f32 [512][64]) -> WT (bf16 [col=64][k=512], swizzled)
    for (int i4 = tid; i4 < (KDIM * EMB) / 4; i4 += 512) {
        f32x4 wv = *reinterpret_cast<const f32x4*>(W + (size_t)i4 * 4);
        int base = i4 * 4;
        int k    = base >> 6;          // 0..511
        int f0   = base & 63;          // output col base (4 consecutive)
        int kblk = k >> 3, klo = k & 7;
#pragma unroll
        for (int j = 0; j < 4; ++j) {
            int col  = f0 + j;
            int eoff = col * KDIM + ((kblk ^ (col & 7)) << 3) + klo;
            WT[eoff] = f2bf(wv[j]);
        }
    }
    __syncthreads();

    const int lane  = tid & 63;
    const int wid   = tid >> 6;
    const int rbase = blockIdx.x * 128 + wid * 16;
    if (rbase >= NNODES) return;

    const int arow = lane & 15;        // A row / B col / C col within tile
    const int kgrp = lane >> 4;        // 0..3
    const float* hp = H + (size_t)(rbase + arow) * KDIM + kgrp * 8;

    f32x4 acc[4] = {f32x4{}, f32x4{}, f32x4{}, f32x4{}};

#pragma unroll 4
    for (int k0 = 0; k0 < KDIM; k0 += 32) {
        // A fragment: H[rbase+arow][k0 + kgrp*8 + 0..7], f32 -> bf16
        f32x4 h0 = *reinterpret_cast<const f32x4*>(hp + k0);
        f32x4 h1 = *reinterpret_cast<const f32x4*>(hp + k0 + 4);
        bf16x8 a;
#pragma unroll
        for (int j = 0; j < 4; ++j) a[j]     = (short)f2bf(h0[j]);
#pragma unroll
        for (int j = 0; j < 4; ++j) a[j + 4] = (short)f2bf(h1[j]);

        const int kblk = (k0 >> 3) + kgrp;     // (k0 + kgrp*8)/8
#pragma unroll
        for (int t = 0; t < 4; ++t) {
            const int col  = t * 16 + arow;
            const int eoff = col * KDIM + ((kblk ^ (col & 7)) << 3);
            bf16x8 b = *reinterpret_cast<const bf16x8*>(&WT[eoff]);
            acc[t] = __builtin_amdgcn_mfma_f32_16x16x32_bf16(a, b, acc[t], 0, 0, 0);
        }
    }

    // C/D: col = lane&15 (within tile), row = (lane>>4)*4 + reg
#pragma unroll
    for (int t = 0; t < 4; ++t) {
#pragma unroll
        for (int i = 0; i < 4; ++i) {
            int row = rbase + kgrp * 4 + i;
            int col = t * 16 + arow;
            out[(size_t)row * EMB + col] = fmaxf(acc[t][i], 0.f);
        }
    }
}

// ---------------------------------------------------------------------------
extern "C" void kernel_launch(void* const* d_in, const int* in_sizes, int n_in,
                              void* d_out, int out_size, void* d_ws, size_t ws_size,
                              hipStream_t stream) {
    const float* x    = (const float*)d_in[0];
    const float* w    = (const float*)d_in[1];
    const int*   rows = (const int*)d_in[2];   // JAX x64-disabled -> int32
    const int*   cols = (const int*)d_in[3];
    float*       out  = (float*)d_out;
    int E = in_sizes[2];

    int*   deg = (int*)d_ws;
    float* H   = (float*)((char*)d_ws + (size_t)RN * sizeof(int));  // 3.2MB offset

    size_t zero_bytes = (size_t)RN * sizeof(int) + (size_t)NNODES * KDIM * sizeof(float);
    hipMemsetAsync(d_ws, 0, zero_bytes, stream);

    k_degree<<<(E + 255) / 256, 256, 0, stream>>>(rows, deg, E);
    k_scatter<<<(E + 3) / 4, 256, 0, stream>>>(rows, cols, deg, x, H, E);

    int gblocks = (NNODES + 127) / 128;   // 782
    k_gemm_mfma<<<gblocks, 512, 0, stream>>>(H, w, out);
}

// Round 3
// 329.901 us; speedup vs baseline: 2.9997x; 1.0494x over previous
//
#include <hip/hip_runtime.h>

#define NNODES 100000
#define NREL 8
#define EMB 64
#define RN (NREL * NNODES)          // 800000 rows of h
#define KDIM (NREL * EMB)           // 512 reduction dim for fused GEMM
#define NB_SCAN ((RN + 1023) / 1024) // 782 scan blocks

typedef __attribute__((ext_vector_type(8))) short bf16x8;   // 8 bf16 (4 VGPRs)
typedef __attribute__((ext_vector_type(4))) float f32x4;

__device__ inline unsigned short f2bf(float f) {
    union { float f; unsigned u; } v; v.f = f;
    return (unsigned short)((v.u + 0x7FFFu + ((v.u >> 16) & 1u)) >> 16);  // RNE
}

// ---------------------------------------------------------------------------
// K1: degree count per (relation,target) row
// ---------------------------------------------------------------------------
__global__ void k_degree(const int* __restrict__ rows, int* __restrict__ deg, int E) {
    int e = blockIdx.x * blockDim.x + threadIdx.x;
    if (e < E) atomicAdd(&deg[rows[e]], 1);
}

// ---------------------------------------------------------------------------
// Scan step 1: per-1024-chunk sums
// ---------------------------------------------------------------------------
__global__ void k_bsum(const int* __restrict__ deg, int* __restrict__ bsum) {
    int t = threadIdx.x;
    int base = blockIdx.x * 1024 + t * 4;     // RN % 4 == 0 -> all-or-nothing
    int s = 0;
    if (base < RN) { int4 v = *reinterpret_cast<const int4*>(deg + base); s = v.x + v.y + v.z + v.w; }
#pragma unroll
    for (int d = 1; d < 64; d <<= 1) s += __shfl_xor(s, d);
    __shared__ int ws[4];
    if ((t & 63) == 0) ws[t >> 6] = s;
    __syncthreads();
    if (t == 0) bsum[blockIdx.x] = ws[0] + ws[1] + ws[2] + ws[3];
}

// ---------------------------------------------------------------------------
// Scan step 2: exclusive scan of the 782 chunk sums (single block)
// ---------------------------------------------------------------------------
__global__ void k_scan_mid(const int* __restrict__ bsum, int* __restrict__ boff) {
    __shared__ int tmp[1024];
    int t = threadIdx.x;
    int v0 = (t < NB_SCAN) ? bsum[t] : 0;
    tmp[t] = v0;
    __syncthreads();
    for (int d = 1; d < 1024; d <<= 1) {
        int u = (t >= d) ? tmp[t - d] : 0;
        __syncthreads();
        tmp[t] += u;
        __syncthreads();
    }
    if (t < NB_SCAN) boff[t] = tmp[t] - v0;   // exclusive
}

// ---------------------------------------------------------------------------
// Scan step 3: full exclusive row_ptr (start offsets)
// ---------------------------------------------------------------------------
__global__ void k_rowptr(const int* __restrict__ deg, const int* __restrict__ boff,
                         int* __restrict__ row_ptr) {
    int t = threadIdx.x;
    int base = blockIdx.x * 1024 + t * 4;
    int4 v = {0, 0, 0, 0};
    if (base < RN) v = *reinterpret_cast<const int4*>(deg + base);
    int s = v.x + v.y + v.z + v.w;
    int lane = t & 63;
    int inc = s;
#pragma unroll
    for (int d = 1; d < 64; d <<= 1) { int u = __shfl_up(inc, d); if (lane >= d) inc += u; }
    __shared__ int ws[4];
    if (lane == 63) ws[t >> 6] = inc;
    __syncthreads();
    int off = boff[blockIdx.x];
    int wid = t >> 6;
    for (int i = 0; i < wid; ++i) off += ws[i];
    int run = off + inc - s;                  // exclusive prefix for this thread
    if (base < RN) {
        int4 o;
        o.x = run; run += v.x;
        o.y = run; run += v.y;
        o.z = run; run += v.z;
        o.w = run;
        *reinterpret_cast<int4*>(row_ptr + base) = o;
    }
}

// ---------------------------------------------------------------------------
// Counting-sort scatter. Mutates row_ptr: afterwards row_ptr[row] == row END,
// so gather uses [row_ptr[row-1], row_ptr[row]).
// ---------------------------------------------------------------------------
__global__ void k_sort(const int* __restrict__ rows, const int* __restrict__ cols,
                       int* __restrict__ row_ptr, int* __restrict__ scols, int E) {
    int e = blockIdx.x * blockDim.x + threadIdx.x;
    if (e < E) {
        int p = atomicAdd(&row_ptr[rows[e]], 1);
        scols[p] = cols[e];
    }
}

// ---------------------------------------------------------------------------
// Gather: one wave per CSR row; lane = emb dim. f32 accumulate, bf16 store.
// No atomics; every H element written (zeros for empty rows).
// ---------------------------------------------------------------------------
__global__ void k_gather(const int* __restrict__ row_ptr, const int* __restrict__ scols,
                         const float* __restrict__ x, unsigned short* __restrict__ Hb) {
    int row = blockIdx.x * (blockDim.x >> 6) + (threadIdx.x >> 6);
    if (row >= RN) return;
    int f = threadIdx.x & 63;
    int s = (row == 0) ? 0 : row_ptr[row - 1];
    int e = row_ptr[row];
    float acc = 0.f;
    for (int i = s; i < e; ++i) {
        int c = scols[i];                       // wave-uniform -> broadcast
        acc += x[(size_t)c * EMB + f];
    }
    float inv = (e > s) ? 1.0f / (float)(e - s) : 0.f;
    acc *= inv;
    int r = row / NNODES;                       // row = r*N + n
    int n = row - r * NNODES;
    Hb[(size_t)n * KDIM + r * EMB + f] = f2bf(acc);
}

// ---------------------------------------------------------------------------
// GEMM: out = relu(Hb[N,512](bf16) @ Wflat[512,64]) via bf16 MFMA 16x16x32.
// Block = 512 thr (8 waves); wave computes 16 rows x 64 cols (4 C-tiles).
// W staged once/block into LDS as bf16 [col][k], XOR-swizzled per 8-k block.
// ---------------------------------------------------------------------------
__global__ __launch_bounds__(512, 4) void k_gemm_mfma(const unsigned short* __restrict__ Hb,
                                                      const float* __restrict__ W,
                                                      float* __restrict__ out) {
    __shared__ unsigned short WT[EMB * KDIM];   // 64 KiB
    const int tid = threadIdx.x;

    for (int i4 = tid; i4 < (KDIM * EMB) / 4; i4 += 512) {
        f32x4 wv = *reinterpret_cast<const f32x4*>(W + (size_t)i4 * 4);
        int base = i4 * 4;
        int k    = base >> 6;
        int f0   = base & 63;
        int kblk = k >> 3, klo = k & 7;
#pragma unroll
        for (int j = 0; j < 4; ++j) {
            int col  = f0 + j;
            int eoff = col * KDIM + ((kblk ^ (col & 7)) << 3) + klo;
            WT[eoff] = f2bf(wv[j]);
        }
    }
    __syncthreads();

    const int lane  = tid & 63;
    const int wid   = tid >> 6;
    const int rbase = blockIdx.x * 128 + wid * 16;
    if (rbase >= NNODES) return;

    const int arow = lane & 15;
    const int kgrp = lane >> 4;
    const unsigned short* hp = Hb + (size_t)(rbase + arow) * KDIM + kgrp * 8;

    f32x4 acc[4] = {f32x4{}, f32x4{}, f32x4{}, f32x4{}};

#pragma unroll 4
    for (int k0 = 0; k0 < KDIM; k0 += 32) {
        bf16x8 a = *reinterpret_cast<const bf16x8*>(hp + k0);
        const int kblk = (k0 >> 3) + kgrp;
#pragma unroll
        for (int t = 0; t < 4; ++t) {
            const int col  = t * 16 + arow;
            const int eoff = col * KDIM + ((kblk ^ (col & 7)) << 3);
            bf16x8 b = *reinterpret_cast<const bf16x8*>(&WT[eoff]);
            acc[t] = __builtin_amdgcn_mfma_f32_16x16x32_bf16(a, b, acc[t], 0, 0, 0);
        }
    }

#pragma unroll
    for (int t = 0; t < 4; ++t) {
#pragma unroll
        for (int i = 0; i < 4; ++i) {
            int row = rbase + kgrp * 4 + i;
            int col = t * 16 + arow;
            out[(size_t)row * EMB + col] = fmaxf(acc[t][i], 0.f);
        }
    }
}

// ---------------------------------------------------------------------------
extern "C" void kernel_launch(void* const* d_in, const int* in_sizes, int n_in,
                              void* d_out, int out_size, void* d_ws, size_t ws_size,
                              hipStream_t stream) {
    const float* x    = (const float*)d_in[0];
    const float* w    = (const float*)d_in[1];
    const int*   rows = (const int*)d_in[2];   // JAX x64-disabled -> int32
    const int*   cols = (const int*)d_in[3];
    float*       out  = (float*)d_out;
    int E = in_sizes[2];

    char* ws = (char*)d_ws;
    int*            deg   = (int*)(ws);                    // 3.2 MB
    int*            rptr  = (int*)(ws + 3200000);          // 3.2 MB
    int*            bsum  = (int*)(ws + 6400000);          // 4 KB
    int*            boff  = (int*)(ws + 6404096);          // 4 KB
    int*            scols = (int*)(ws + 6408192);          // 4 MB
    unsigned short* Hb    = (unsigned short*)(ws + 10408192); // 102.4 MB

    hipMemsetAsync(deg, 0, (size_t)RN * sizeof(int), stream);

    k_degree<<<(E + 255) / 256, 256, 0, stream>>>(rows, deg, E);
    k_bsum<<<NB_SCAN, 256, 0, stream>>>(deg, bsum);
    k_scan_mid<<<1, 1024, 0, stream>>>(bsum, boff);
    k_rowptr<<<NB_SCAN, 256, 0, stream>>>(deg, boff, rptr);
    k_sort<<<(E + 255) / 256, 256, 0, stream>>>(rows, cols, rptr, scols, E);
    k_gather<<<(RN + 3) / 4, 256, 0, stream>>>(rptr, scols, x, Hb);
    k_gemm_mfma<<<(NNODES + 127) / 128, 512, 0, stream>>>(Hb, w, out);
}

// Round 4
// 245.092 us; speedup vs baseline: 4.0376x; 1.3460x over previous
//
#include <hip/hip_runtime.h>

#define NNODES 100000
#define NREL 8
#define EMB 64
#define RN (NREL * NNODES)           // 800000 CSR rows (node-major keys n*8+r)
#define KDIM (NREL * EMB)            // 512 reduction dim for fused GEMM
#define NB_SCAN ((RN + 1023) / 1024) // 782 scan blocks

typedef __attribute__((ext_vector_type(8))) short bf16x8;   // 8 bf16 (4 VGPRs)
typedef __attribute__((ext_vector_type(4))) float f32x4;

__device__ inline unsigned short f2bf(float f) {
    union { float f; unsigned u; } v; v.f = f;
    return (unsigned short)((v.u + 0x7FFFu + ((v.u >> 16) & 1u)) >> 16);  // RNE
}

// edge row (r*N + n)  ->  node-major key (n*8 + r)
__device__ inline int edge_key(int row) {
    int r = row / NNODES;            // magic-mul
    int n = row - r * NNODES;
    return n * NREL + r;
}

// ---------------------------------------------------------------------------
// K1: degree count per node-major key
// ---------------------------------------------------------------------------
__global__ void k_degree(const int* __restrict__ rows, int* __restrict__ deg, int E) {
    int e = blockIdx.x * blockDim.x + threadIdx.x;
    if (e < E) atomicAdd(&deg[edge_key(rows[e])], 1);
}

// ---------------------------------------------------------------------------
// Scan step 1: per-1024-chunk sums
// ---------------------------------------------------------------------------
__global__ void k_bsum(const int* __restrict__ deg, int* __restrict__ bsum) {
    int t = threadIdx.x;
    int base = blockIdx.x * 1024 + t * 4;     // RN % 4 == 0 -> all-or-nothing
    int s = 0;
    if (base < RN) { int4 v = *reinterpret_cast<const int4*>(deg + base); s = v.x + v.y + v.z + v.w; }
#pragma unroll
    for (int d = 1; d < 64; d <<= 1) s += __shfl_xor(s, d);
    __shared__ int ws[4];
    if ((t & 63) == 0) ws[t >> 6] = s;
    __syncthreads();
    if (t == 0) bsum[blockIdx.x] = ws[0] + ws[1] + ws[2] + ws[3];
}

// ---------------------------------------------------------------------------
// Scan step 2: exclusive scan of the 782 chunk sums (single block)
// ---------------------------------------------------------------------------
__global__ void k_scan_mid(const int* __restrict__ bsum, int* __restrict__ boff) {
    __shared__ int tmp[1024];
    int t = threadIdx.x;
    int v0 = (t < NB_SCAN) ? bsum[t] : 0;
    tmp[t] = v0;
    __syncthreads();
    for (int d = 1; d < 1024; d <<= 1) {
        int u = (t >= d) ? tmp[t - d] : 0;
        __syncthreads();
        tmp[t] += u;
        __syncthreads();
    }
    if (t < NB_SCAN) boff[t] = tmp[t] - v0;   // exclusive
}

// ---------------------------------------------------------------------------
// Scan step 3: full exclusive row_ptr (start offsets)
// ---------------------------------------------------------------------------
__global__ void k_rowptr(const int* __restrict__ deg, const int* __restrict__ boff,
                         int* __restrict__ row_ptr) {
    int t = threadIdx.x;
    int base = blockIdx.x * 1024 + t * 4;
    int4 v = {0, 0, 0, 0};
    if (base < RN) v = *reinterpret_cast<const int4*>(deg + base);
    int s = v.x + v.y + v.z + v.w;
    int lane = t & 63;
    int inc = s;
#pragma unroll
    for (int d = 1; d < 64; d <<= 1) { int u = __shfl_up(inc, d); if (lane >= d) inc += u; }
    __shared__ int ws[4];
    if (lane == 63) ws[t >> 6] = inc;
    __syncthreads();
    int off = boff[blockIdx.x];
    int wid = t >> 6;
    for (int i = 0; i < wid; ++i) off += ws[i];
    int run = off + inc - s;                  // exclusive prefix for this thread
    if (base < RN) {
        int4 o;
        o.x = run; run += v.x;
        o.y = run; run += v.y;
        o.z = run; run += v.z;
        o.w = run;
        *reinterpret_cast<int4*>(row_ptr + base) = o;
    }
}

// ---------------------------------------------------------------------------
// Counting-sort scatter. Mutates row_ptr: afterwards row_ptr[key] == segment
// END, so gather uses [row_ptr[key-1], row_ptr[key]).
// ---------------------------------------------------------------------------
__global__ void k_sort(const int* __restrict__ rows, const int* __restrict__ cols,
                       int* __restrict__ row_ptr, int* __restrict__ scols, int E) {
    int e = blockIdx.x * blockDim.x + threadIdx.x;
    if (e < E) {
        int p = atomicAdd(&row_ptr[edge_key(rows[e])], 1);
        scols[p] = cols[e];
    }
}

// ---------------------------------------------------------------------------
// Gather: one wave per NODE (8 relation segments, contiguous in CSR).
// lane = emb dim f. Cols vector-loaded once; edges processed in chunks of 8
// independent x loads; accumulate into 8 static per-relation registers via
// wave-uniform relation selects. Store: lane packs its 8 relation values as
// one bf16x8 -> Hb[n][f*8+r] (k' = (j,r) permuted layout, 16B store).
// ---------------------------------------------------------------------------
__global__ void k_gather(const int* __restrict__ row_ptr, const int* __restrict__ scols,
                         const float* __restrict__ x, unsigned short* __restrict__ Hb) {
    int n = blockIdx.x * (blockDim.x >> 6) + (threadIdx.x >> 6);
    if (n >= NNODES) return;
    const int lane = threadIdx.x & 63;

    // boundaries b[0..8]: rptr[n*8-1 .. n*8+7]; b[0]=segment start (0 for n=0)
    int idx = n * NREL - 1 + lane;
    int bv = 0;
    if (lane < 9 && idx >= 0) bv = row_ptr[idx];
    int b[9];
#pragma unroll
    for (int j = 0; j < 9; ++j) b[j] = __shfl(bv, j);
    const int s = b[0];
    const int deg = b[8] - s;
    const int deg64 = deg > 64 ? 64 : deg;

    // per-lane: col of edge (s+lane) and its relation (8 = none)
    int cv = (lane < deg) ? scols[s + lane] : 0;
    int rl = 0;
#pragma unroll
    for (int r = 1; r <= 8; ++r) rl += (lane >= b[r] - s) ? 1 : 0;

    float acc[8] = {0.f, 0.f, 0.f, 0.f, 0.f, 0.f, 0.f, 0.f};

    for (int j0 = 0; j0 < deg64; j0 += 8) {
        float v[8];
        int rr[8];
#pragma unroll
        for (int u = 0; u < 8; ++u) {
            int j = j0 + u; if (j > 63) j = 63;
            int c = __shfl(cv, j);
            rr[u] = __shfl(rl, j);
            if (j0 + u >= deg64) rr[u] = 8;               // wave-uniform kill
            v[u] = x[(size_t)c * EMB + lane];             // independent loads
        }
#pragma unroll
        for (int u = 0; u < 8; ++u) {
#pragma unroll
            for (int r = 0; r < 8; ++r)
                acc[r] += (rr[u] == r) ? v[u] : 0.f;
        }
    }

    if (deg > 64) {   // vanishing-probability slow path, correctness guard
#pragma unroll
        for (int r = 0; r < 8; ++r) {
            int st = b[r] < s + 64 ? s + 64 : b[r];
            for (int i = st; i < b[r + 1]; ++i)
                acc[r] += x[(size_t)scols[i] * EMB + lane];
        }
    }

    bf16x8 hout;
#pragma unroll
    for (int r = 0; r < 8; ++r) {
        int d = b[r + 1] - b[r];
        float val = (d > 0) ? acc[r] * (1.0f / (float)d) : 0.f;
        hout[r] = (short)f2bf(val);
    }
    *reinterpret_cast<bf16x8*>(Hb + (size_t)n * KDIM + lane * NREL) = hout;
}

// ---------------------------------------------------------------------------
// GEMM: out = relu(Hb[N,512](bf16,k'=(j,r) order) @ W'[512,64]) via MFMA.
// Block = 512 thr (8 waves); wave computes 16 rows x 64 cols (4 C-tiles).
// W staged once/block into LDS as bf16 [col][k'], XOR-swizzled per 8-k block;
// k' permutation (original k=r*64+j -> k'=j*8+r) matches Hb layout.
// ---------------------------------------------------------------------------
__global__ __launch_bounds__(512, 4) void k_gemm_mfma(const unsigned short* __restrict__ Hb,
                                                      const float* __restrict__ W,
                                                      float* __restrict__ out) {
    __shared__ unsigned short WT[EMB * KDIM];   // 64 KiB
    const int tid = threadIdx.x;

    for (int i4 = tid; i4 < (KDIM * EMB) / 4; i4 += 512) {
        f32x4 wv = *reinterpret_cast<const f32x4*>(W + (size_t)i4 * 4);
        int base = i4 * 4;
        int k    = base >> 6;          // original k = r*64 + j
        int f0   = base & 63;
        int r    = k >> 6;             // 0..7  -> k' low bits
        int j    = k & 63;             // 0..63 -> k' block index (kblk'=j)
#pragma unroll
        for (int jj = 0; jj < 4; ++jj) {
            int col  = f0 + jj;
            int eoff = col * KDIM + ((j ^ (col & 7)) << 3) + r;
            WT[eoff] = f2bf(wv[jj]);
        }
    }
    __syncthreads();

    const int lane  = tid & 63;
    const int wid   = tid >> 6;
    const int rbase = blockIdx.x * 128 + wid * 16;
    if (rbase >= NNODES) return;

    const int arow = lane & 15;
    const int kgrp = lane >> 4;
    const unsigned short* hp = Hb + (size_t)(rbase + arow) * KDIM + kgrp * 8;

    f32x4 acc[4] = {f32x4{}, f32x4{}, f32x4{}, f32x4{}};

#pragma unroll 4
    for (int k0 = 0; k0 < KDIM; k0 += 32) {
        bf16x8 a = *reinterpret_cast<const bf16x8*>(hp + k0);
        const int kblk = (k0 >> 3) + kgrp;
#pragma unroll
        for (int t = 0; t < 4; ++t) {
            const int col  = t * 16 + arow;
            const int eoff = col * KDIM + ((kblk ^ (col & 7)) << 3);
            bf16x8 b = *reinterpret_cast<const bf16x8*>(&WT[eoff]);
            acc[t] = __builtin_amdgcn_mfma_f32_16x16x32_bf16(a, b, acc[t], 0, 0, 0);
        }
    }

#pragma unroll
    for (int t = 0; t < 4; ++t) {
#pragma unroll
        for (int i = 0; i < 4; ++i) {
            int row = rbase + kgrp * 4 + i;
            int col = t * 16 + arow;
            out[(size_t)row * EMB + col] = fmaxf(acc[t][i], 0.f);
        }
    }
}

// ---------------------------------------------------------------------------
extern "C" void kernel_launch(void* const* d_in, const int* in_sizes, int n_in,
                              void* d_out, int out_size, void* d_ws, size_t ws_size,
                              hipStream_t stream) {
    const float* x    = (const float*)d_in[0];
    const float* w    = (const float*)d_in[1];
    const int*   rows = (const int*)d_in[2];   // JAX x64-disabled -> int32
    const int*   cols = (const int*)d_in[3];
    float*       out  = (float*)d_out;
    int E = in_sizes[2];

    char* ws = (char*)d_ws;
    int*            deg   = (int*)(ws);                    // 3.2 MB
    int*            rptr  = (int*)(ws + 3200000);          // 3.2 MB
    int*            bsum  = (int*)(ws + 6400000);          // 4 KB
    int*            boff  = (int*)(ws + 6404096);          // 4 KB
    int*            scols = (int*)(ws + 6408192);          // 4 MB
    unsigned short* Hb    = (unsigned short*)(ws + 10408192); // 102.4 MB

    hipMemsetAsync(deg, 0, (size_t)RN * sizeof(int), stream);

    k_degree<<<(E + 255) / 256, 256, 0, stream>>>(rows, deg, E);
    k_bsum<<<NB_SCAN, 256, 0, stream>>>(deg, bsum);
    k_scan_mid<<<1, 1024, 0, stream>>>(bsum, boff);
    k_rowptr<<<NB_SCAN, 256, 0, stream>>>(deg, boff, rptr);
    k_sort<<<(E + 255) / 256, 256, 0, stream>>>(rows, cols, rptr, scols, E);
    k_gather<<<(NNODES + 3) / 4, 256, 0, stream>>>(rptr, scols, x, Hb);
    k_gemm_mfma<<<(NNODES + 127) / 128, 512, 0, stream>>>(Hb, w, out);
}

// Round 5
// 197.306 us; speedup vs baseline: 5.0155x; 1.2422x over previous
//
#include <hip/hip_runtime.h>

#define NNODES 100000
#define NREL 8
#define EMB 64
#define RN (NREL * NNODES)           // 800000 CSR segments (keys n*8+r)
#define YDIM (NREL * EMB)            // 512
#define NB_SCAN ((RN + 1023) / 1024) // 782 scan blocks

typedef __attribute__((ext_vector_type(8))) short bf16x8;   // 8 bf16 (4 VGPRs)
typedef __attribute__((ext_vector_type(4))) float f32x4;

__device__ inline unsigned short f2bf(float f) {
    union { float f; unsigned u; } v; v.f = f;
    return (unsigned short)((v.u + 0x7FFFu + ((v.u >> 16) & 1u)) >> 16);  // RNE
}
__device__ inline float bf2f(unsigned short u) {
    union { unsigned u; float f; } v; v.u = ((unsigned)u) << 16; return v.f;
}

// ---------------------------------------------------------------------------
// K1: degree count per node-major key (n*8 + r)
// ---------------------------------------------------------------------------
__global__ void k_degree(const int* __restrict__ rows, int* __restrict__ deg, int E) {
    int e = blockIdx.x * blockDim.x + threadIdx.x;
    if (e < E) {
        int row = rows[e];
        int r = row / NNODES;            // magic-mul
        int n = row - r * NNODES;
        atomicAdd(&deg[n * NREL + r], 1);
    }
}

// ---------------------------------------------------------------------------
// Scan step 1: per-1024-chunk sums
// ---------------------------------------------------------------------------
__global__ void k_bsum(const int* __restrict__ deg, int* __restrict__ bsum) {
    int t = threadIdx.x;
    int base = blockIdx.x * 1024 + t * 4;
    int s = 0;
    if (base < RN) { int4 v = *reinterpret_cast<const int4*>(deg + base); s = v.x + v.y + v.z + v.w; }
#pragma unroll
    for (int d = 1; d < 64; d <<= 1) s += __shfl_xor(s, d);
    __shared__ int ws[4];
    if ((t & 63) == 0) ws[t >> 6] = s;
    __syncthreads();
    if (t == 0) bsum[blockIdx.x] = ws[0] + ws[1] + ws[2] + ws[3];
}

// ---------------------------------------------------------------------------
// Scan step 2: exclusive scan of the 782 chunk sums (single block)
// ---------------------------------------------------------------------------
__global__ void k_scan_mid(const int* __restrict__ bsum, int* __restrict__ boff) {
    __shared__ int tmp[1024];
    int t = threadIdx.x;
    int v0 = (t < NB_SCAN) ? bsum[t] : 0;
    tmp[t] = v0;
    __syncthreads();
    for (int d = 1; d < 1024; d <<= 1) {
        int u = (t >= d) ? tmp[t - d] : 0;
        __syncthreads();
        tmp[t] += u;
        __syncthreads();
    }
    if (t < NB_SCAN) boff[t] = tmp[t] - v0;   // exclusive
}

// ---------------------------------------------------------------------------
// Scan step 3: full exclusive row_ptr (start offsets)
// ---------------------------------------------------------------------------
__global__ void k_rowptr(const int* __restrict__ deg, const int* __restrict__ boff,
                         int* __restrict__ row_ptr) {
    int t = threadIdx.x;
    int base = blockIdx.x * 1024 + t * 4;
    int4 v = {0, 0, 0, 0};
    if (base < RN) v = *reinterpret_cast<const int4*>(deg + base);
    int s = v.x + v.y + v.z + v.w;
    int lane = t & 63;
    int inc = s;
#pragma unroll
    for (int d = 1; d < 64; d <<= 1) { int u = __shfl_up(inc, d); if (lane >= d) inc += u; }
    __shared__ int ws[4];
    if (lane == 63) ws[t >> 6] = inc;
    __syncthreads();
    int off = boff[blockIdx.x];
    int wid = t >> 6;
    for (int i = 0; i < wid; ++i) off += ws[i];
    int run = off + inc - s;                  // exclusive prefix for this thread
    if (base < RN) {
        int4 o;
        o.x = run; run += v.x;
        o.y = run; run += v.y;
        o.z = run; run += v.z;
        o.w = run;
        *reinterpret_cast<int4*>(row_ptr + base) = o;
    }
}

// ---------------------------------------------------------------------------
// Counting-sort scatter of per-edge payload {packed_src = c*8+r, inv_deg}.
// Mutates row_ptr: afterwards row_ptr[key] == segment END.
// ---------------------------------------------------------------------------
__global__ void k_sort(const int* __restrict__ rows, const int* __restrict__ cols,
                       const int* __restrict__ deg, int* __restrict__ rptr,
                       int2* __restrict__ pairs, int E) {
    int e = blockIdx.x * blockDim.x + threadIdx.x;
    if (e >= E) return;
    int row = rows[e];
    int r = row / NNODES;
    int n = row - r * NNODES;
    int key = n * NREL + r;
    int p = atomicAdd(&rptr[key], 1);
    float inv = __builtin_amdgcn_rcpf((float)deg[key]);   // deg>=1 for this key
    pairs[p] = make_int2(cols[e] * NREL + r, __float_as_int(inv));
}

// ---------------------------------------------------------------------------
// GEMM1: y[c, r*64+f] = sum_k x[c,k] * W[r,k,f]   (bf16 MFMA 16x16x32, K=64)
// Block = 512 thr (8 waves); wave = one relation, 128 nodes (8 row-tiles).
// W (128 KB f32) staged once/block into LDS bf16 [r][f][k], XOR-swizzled.
// ---------------------------------------------------------------------------
__global__ __launch_bounds__(512, 4) void k_gemm1(const float* __restrict__ x,
                                                  const float* __restrict__ W,
                                                  unsigned short* __restrict__ y) {
    __shared__ unsigned short WT[NREL * EMB * EMB];   // 64 KiB
    const int tid = threadIdx.x;

    for (int i4 = tid; i4 < (NREL * EMB * EMB) / 4; i4 += 512) {
        f32x4 wv = *reinterpret_cast<const f32x4*>(W + (size_t)i4 * 4);
        int base = i4 * 4;                 // flat = ((r*64)+k)*64 + f
        int f0 = base & 63;
        int k  = (base >> 6) & 63;
        int r  = base >> 12;
#pragma unroll
        for (int j = 0; j < 4; ++j) {
            int col = f0 + j;
            WT[((r * EMB + col) << 6) + (((k >> 3) ^ (col & 7)) << 3) + (k & 7)] = f2bf(wv[j]);
        }
    }
    __syncthreads();

    const int lane = tid & 63;
    const int rel  = tid >> 6;             // wave id = relation
    const int arow = lane & 15;
    const int kgrp = lane >> 4;
    const int nbase = blockIdx.x * 128;

    for (int rt = 0; rt < 8; ++rt) {
        int n  = nbase + rt * 16 + arow;
        int nc = n < NNODES ? n : NNODES - 1;
        const float* xp = x + (size_t)nc * EMB + kgrp * 8;
        f32x4 a0 = *reinterpret_cast<const f32x4*>(xp);
        f32x4 a1 = *reinterpret_cast<const f32x4*>(xp + 4);
        f32x4 a2 = *reinterpret_cast<const f32x4*>(xp + 32);
        f32x4 a3 = *reinterpret_cast<const f32x4*>(xp + 36);
        bf16x8 A0, A1;
#pragma unroll
        for (int j = 0; j < 4; ++j) {
            A0[j]     = (short)f2bf(a0[j]);  A0[j + 4] = (short)f2bf(a1[j]);
            A1[j]     = (short)f2bf(a2[j]);  A1[j + 4] = (short)f2bf(a3[j]);
        }

        f32x4 acc[4] = {f32x4{}, f32x4{}, f32x4{}, f32x4{}};
#pragma unroll
        for (int ct = 0; ct < 4; ++ct) {
            int col   = ct * 16 + arow;
            int cbase = (rel * EMB + col) << 6;
            int sw    = col & 7;
            bf16x8 b0 = *reinterpret_cast<const bf16x8*>(&WT[cbase + ((kgrp ^ sw) << 3)]);
            acc[ct] = __builtin_amdgcn_mfma_f32_16x16x32_bf16(A0, b0, acc[ct], 0, 0, 0);
            bf16x8 b1 = *reinterpret_cast<const bf16x8*>(&WT[cbase + (((4 + kgrp) ^ sw) << 3)]);
            acc[ct] = __builtin_amdgcn_mfma_f32_16x16x32_bf16(A1, b1, acc[ct], 0, 0, 0);
        }

        // C/D: col = lane&15 (tile-local), row = kgrp*4 + i
#pragma unroll
        for (int ct = 0; ct < 4; ++ct) {
#pragma unroll
            for (int i = 0; i < 4; ++i) {
                int nr = nbase + rt * 16 + kgrp * 4 + i;
                if (nr < NNODES) {
                    int col = ct * 16 + arow;
                    y[(size_t)nr * YDIM + rel * EMB + col] = f2bf(acc[ct][i]);
                }
            }
        }
    }
}

// ---------------------------------------------------------------------------
// Gather: one wave per node; lane = output dim f. Per edge: uniform scalar
// {packed, inv} via readlane -> scalar-base ushort load of y[packed*64+f],
// acc = fmaf(inv, v, acc). 8 independent loads in flight per chunk.
// Writes final out = relu(acc) directly.
// ---------------------------------------------------------------------------
__global__ void k_gather(const int* __restrict__ rptr, const int2* __restrict__ pairs,
                         const unsigned short* __restrict__ yb, float* __restrict__ out) {
    int n = blockIdx.x * (blockDim.x >> 6) + (threadIdx.x >> 6);
    if (n >= NNODES) return;
    const int lane = threadIdx.x & 63;

    int s = (n == 0) ? 0 : rptr[n * NREL - 1];     // wave-uniform broadcast loads
    int e = rptr[n * NREL + NREL - 1];

    float acc = 0.f;
    for (int c0 = s; c0 < e; c0 += 64) {
        int m = e - c0; if (m > 64) m = 64;
        int2 pv = (lane < m) ? pairs[c0 + lane] : make_int2(0, 0);
        for (int j0 = 0; j0 < m; j0 += 8) {
#pragma unroll
            for (int u = 0; u < 8; ++u) {
                int j  = j0 + u;
                int jc = j < m ? j : 0;                         // uniform clamp
                int sp = __builtin_amdgcn_readlane(pv.x, jc);   // scalar packed
                int sb = __builtin_amdgcn_readlane(pv.y, jc);   // scalar inv bits
                float si = (j < m) ? __int_as_float(sb) : 0.f;  // dead edge -> *0
                float v  = bf2f(yb[(size_t)sp * EMB + lane]);
                acc = fmaf(si, v, acc);
            }
        }
    }
    out[(size_t)n * EMB + lane] = fmaxf(acc, 0.f);
}

// ---------------------------------------------------------------------------
extern "C" void kernel_launch(void* const* d_in, const int* in_sizes, int n_in,
                              void* d_out, int out_size, void* d_ws, size_t ws_size,
                              hipStream_t stream) {
    const float* x    = (const float*)d_in[0];
    const float* w    = (const float*)d_in[1];
    const int*   rows = (const int*)d_in[2];   // JAX x64-disabled -> int32
    const int*   cols = (const int*)d_in[3];
    float*       out  = (float*)d_out;
    int E = in_sizes[2];

    char* ws = (char*)d_ws;
    int*            deg   = (int*)(ws);                       // 3.2 MB
    int*            rptr  = (int*)(ws + 3200000);             // 3.2 MB
    int*            bsum  = (int*)(ws + 6400000);             // 4 KB
    int*            boff  = (int*)(ws + 6404096);             // 4 KB
    int2*           pairs = (int2*)(ws + 6408192);            // 8 MB
    unsigned short* y     = (unsigned short*)(ws + 14408192); // 102.4 MB

    hipMemsetAsync(deg, 0, (size_t)RN * sizeof(int), stream);

    k_degree<<<(E + 255) / 256, 256, 0, stream>>>(rows, deg, E);
    k_bsum<<<NB_SCAN, 256, 0, stream>>>(deg, bsum);
    k_scan_mid<<<1, 1024, 0, stream>>>(bsum, boff);
    k_rowptr<<<NB_SCAN, 256, 0, stream>>>(deg, boff, rptr);
    k_sort<<<(E + 255) / 256, 256, 0, stream>>>(rows, cols, deg, rptr, pairs, E);
    k_gemm1<<<(NNODES + 127) / 128, 512, 0, stream>>>(x, w, y);
    k_gather<<<(NNODES + 3) / 4, 256, 0, stream>>>(rptr, pairs, y, out);
}

// Round 6
// 192.008 us; speedup vs baseline: 5.1539x; 1.0276x over previous
//
#include <hip/hip_runtime.h>

#define NNODES 100000
#define NREL 8
#define EMB 64
#define RN (NREL * NNODES)           // 800000 CSR segments (keys n*8+r)
#define YDIM (NREL * EMB)            // 512
#define NB_SCAN ((RN + 1023) / 1024) // 782 scan blocks
#define NSTRIPS (NNODES / 16)        // 6250, exact
#define G1_BLOCKS 1250               // 5 strips per block, exact

typedef __attribute__((ext_vector_type(8))) short bf16x8;   // 8 bf16 (4 VGPRs)
typedef __attribute__((ext_vector_type(4))) float f32x4;

__device__ inline unsigned short f2bf(float f) {
    union { float f; unsigned u; } v; v.f = f;
    return (unsigned short)((v.u + 0x7FFFu + ((v.u >> 16) & 1u)) >> 16);  // RNE
}
__device__ inline float bf2f(unsigned short u) {
    union { unsigned u; float f; } v; v.u = ((unsigned)u) << 16; return v.f;
}

// ---------------------------------------------------------------------------
// K1: degree count per node-major key (n*8 + r)
// ---------------------------------------------------------------------------
__global__ void k_degree(const int* __restrict__ rows, int* __restrict__ deg, int E) {
    int e = blockIdx.x * blockDim.x + threadIdx.x;
    if (e < E) {
        int row = rows[e];
        int r = row / NNODES;            // magic-mul
        int n = row - r * NNODES;
        atomicAdd(&deg[n * NREL + r], 1);
    }
}

// ---------------------------------------------------------------------------
// Scan step 1: per-1024-chunk sums
// ---------------------------------------------------------------------------
__global__ void k_bsum(const int* __restrict__ deg, int* __restrict__ bsum) {
    int t = threadIdx.x;
    int base = blockIdx.x * 1024 + t * 4;
    int s = 0;
    if (base < RN) { int4 v = *reinterpret_cast<const int4*>(deg + base); s = v.x + v.y + v.z + v.w; }
#pragma unroll
    for (int d = 1; d < 64; d <<= 1) s += __shfl_xor(s, d);
    __shared__ int ws[4];
    if ((t & 63) == 0) ws[t >> 6] = s;
    __syncthreads();
    if (t == 0) bsum[blockIdx.x] = ws[0] + ws[1] + ws[2] + ws[3];
}

// ---------------------------------------------------------------------------
// Scan step 2: exclusive scan of the 782 chunk sums (single block)
// ---------------------------------------------------------------------------
__global__ void k_scan_mid(const int* __restrict__ bsum, int* __restrict__ boff) {
    __shared__ int tmp[1024];
    int t = threadIdx.x;
    int v0 = (t < NB_SCAN) ? bsum[t] : 0;
    tmp[t] = v0;
    __syncthreads();
    for (int d = 1; d < 1024; d <<= 1) {
        int u = (t >= d) ? tmp[t - d] : 0;
        __syncthreads();
        tmp[t] += u;
        __syncthreads();
    }
    if (t < NB_SCAN) boff[t] = tmp[t] - v0;   // exclusive
}

// ---------------------------------------------------------------------------
// Scan step 3: full exclusive row_ptr (start offsets)
// ---------------------------------------------------------------------------
__global__ void k_rowptr(const int* __restrict__ deg, const int* __restrict__ boff,
                         int* __restrict__ row_ptr) {
    int t = threadIdx.x;
    int base = blockIdx.x * 1024 + t * 4;
    int4 v = {0, 0, 0, 0};
    if (base < RN) v = *reinterpret_cast<const int4*>(deg + base);
    int s = v.x + v.y + v.z + v.w;
    int lane = t & 63;
    int inc = s;
#pragma unroll
    for (int d = 1; d < 64; d <<= 1) { int u = __shfl_up(inc, d); if (lane >= d) inc += u; }
    __shared__ int ws[4];
    if (lane == 63) ws[t >> 6] = inc;
    __syncthreads();
    int off = boff[blockIdx.x];
    int wid = t >> 6;
    for (int i = 0; i < wid; ++i) off += ws[i];
    int run = off + inc - s;                  // exclusive prefix for this thread
    if (base < RN) {
        int4 o;
        o.x = run; run += v.x;
        o.y = run; run += v.y;
        o.z = run; run += v.z;
        o.w = run;
        *reinterpret_cast<int4*>(row_ptr + base) = o;
    }
}

// ---------------------------------------------------------------------------
// Counting-sort scatter of per-edge payload {packed_src = c*8+r, inv_deg}.
// Mutates row_ptr: afterwards row_ptr[key] == segment END.
// ---------------------------------------------------------------------------
__global__ void k_sort(const int* __restrict__ rows, const int* __restrict__ cols,
                       const int* __restrict__ deg, int* __restrict__ rptr,
                       int2* __restrict__ pairs, int E) {
    int e = blockIdx.x * blockDim.x + threadIdx.x;
    if (e >= E) return;
    int row = rows[e];
    int r = row / NNODES;
    int n = row - r * NNODES;
    int key = n * NREL + r;
    int p = atomicAdd(&rptr[key], 1);
    float inv = __builtin_amdgcn_rcpf((float)deg[key]);   // deg>=1 for this key
    pairs[p] = make_int2(cols[e] * NREL + r, __float_as_int(inv));
}

// ---------------------------------------------------------------------------
// GEMM1: y[c, r*64+f] = sum_k x[c,k] * W[r,k,f]   (bf16 MFMA 16x16x32, K=64)
// Swapped-operand form: D[f][c] tiles. A = W^T fragments (strip-invariant,
// held in 32 VGPRs, loaded once per block); B = x row slices loaded DIRECTLY
// from global (16B/lane contiguous). No LDS at all. Epilogue: lane holds 4
// consecutive f per f-tile -> 8B stores (32B contiguous per node).
// Block = 512 thr (8 waves); wave = one relation, 16 nodes/strip; 5 strips.
// ---------------------------------------------------------------------------
__global__ __launch_bounds__(512) void k_gemm1(const float* __restrict__ x,
                                               const float* __restrict__ W,
                                               unsigned short* __restrict__ y) {
    const int lane = threadIdx.x & 63;
    const int rel  = threadIdx.x >> 6;     // wave id = relation
    const int fl   = lane & 15;            // A row (f_local) == B col (c_local)
    const int kgrp = lane >> 4;            // k-group 0..3

    // A fragments: wfrag[ft][ks][j] = W[rel][ks*32 + kgrp*8 + j][ft*16 + fl]
    bf16x8 wfrag[4][2];
#pragma unroll
    for (int ft = 0; ft < 4; ++ft)
#pragma unroll
        for (int ks = 0; ks < 2; ++ks) {
            const float* wp = W + ((size_t)rel * EMB + ks * 32 + kgrp * 8) * EMB
                              + ft * 16 + fl;
            bf16x8 a;
#pragma unroll
            for (int j = 0; j < 8; ++j) a[j] = (short)f2bf(wp[(size_t)j * EMB]);
            wfrag[ft][ks] = a;
        }

    for (int strip = blockIdx.x; strip < NSTRIPS; strip += G1_BLOCKS) {
        const int c = strip * 16 + fl;
        const float* xp = x + (size_t)c * EMB + kgrp * 8;
        f32x4 x0 = *reinterpret_cast<const f32x4*>(xp);        // ks=0
        f32x4 x1 = *reinterpret_cast<const f32x4*>(xp + 4);
        f32x4 x2 = *reinterpret_cast<const f32x4*>(xp + 32);   // ks=1
        f32x4 x3 = *reinterpret_cast<const f32x4*>(xp + 36);
        bf16x8 B0, B1;
#pragma unroll
        for (int j = 0; j < 4; ++j) {
            B0[j] = (short)f2bf(x0[j]);  B0[j + 4] = (short)f2bf(x1[j]);
            B1[j] = (short)f2bf(x2[j]);  B1[j + 4] = (short)f2bf(x3[j]);
        }

        f32x4 acc[4] = {f32x4{}, f32x4{}, f32x4{}, f32x4{}};
#pragma unroll
        for (int ft = 0; ft < 4; ++ft) {
            acc[ft] = __builtin_amdgcn_mfma_f32_16x16x32_bf16(wfrag[ft][0], B0, acc[ft], 0, 0, 0);
            acc[ft] = __builtin_amdgcn_mfma_f32_16x16x32_bf16(wfrag[ft][1], B1, acc[ft], 0, 0, 0);
        }

        // D[f][c]: lane holds col c=fl, rows f = ft*16 + kgrp*4 + i
        unsigned short* yp = y + (size_t)c * YDIM + rel * EMB + kgrp * 4;
#pragma unroll
        for (int ft = 0; ft < 4; ++ft) {
            ushort4 o;
            o.x = f2bf(acc[ft][0]); o.y = f2bf(acc[ft][1]);
            o.z = f2bf(acc[ft][2]); o.w = f2bf(acc[ft][3]);
            *reinterpret_cast<ushort4*>(yp + ft * 16) = o;
        }
    }
}

// ---------------------------------------------------------------------------
// Gather: one wave per node; lane = output dim f. Per edge: uniform scalar
// {packed, inv} via readlane -> scalar-base ushort load of y[packed*64+f],
// acc = fmaf(inv, v, acc). 8 independent loads in flight per chunk.
// Writes final out = relu(acc) directly.
// ---------------------------------------------------------------------------
__global__ void k_gather(const int* __restrict__ rptr, const int2* __restrict__ pairs,
                         const unsigned short* __restrict__ yb, float* __restrict__ out) {
    int n = blockIdx.x * (blockDim.x >> 6) + (threadIdx.x >> 6);
    if (n >= NNODES) return;
    const int lane = threadIdx.x & 63;

    int s = (n == 0) ? 0 : rptr[n * NREL - 1];     // wave-uniform broadcast loads
    int e = rptr[n * NREL + NREL - 1];

    float acc = 0.f;
    for (int c0 = s; c0 < e; c0 += 64) {
        int m = e - c0; if (m > 64) m = 64;
        int2 pv = (lane < m) ? pairs[c0 + lane] : make_int2(0, 0);
        for (int j0 = 0; j0 < m; j0 += 8) {
#pragma unroll
            for (int u = 0; u < 8; ++u) {
                int j  = j0 + u;
                int jc = j < m ? j : 0;                         // uniform clamp
                int sp = __builtin_amdgcn_readlane(pv.x, jc);   // scalar packed
                int sb = __builtin_amdgcn_readlane(pv.y, jc);   // scalar inv bits
                float si = (j < m) ? __int_as_float(sb) : 0.f;  // dead edge -> *0
                float v  = bf2f(yb[(size_t)sp * EMB + lane]);
                acc = fmaf(si, v, acc);
            }
        }
    }
    out[(size_t)n * EMB + lane] = fmaxf(acc, 0.f);
}

// ---------------------------------------------------------------------------
extern "C" void kernel_launch(void* const* d_in, const int* in_sizes, int n_in,
                              void* d_out, int out_size, void* d_ws, size_t ws_size,
                              hipStream_t stream) {
    const float* x    = (const float*)d_in[0];
    const float* w    = (const float*)d_in[1];
    const int*   rows = (const int*)d_in[2];   // JAX x64-disabled -> int32
    const int*   cols = (const int*)d_in[3];
    float*       out  = (float*)d_out;
    int E = in_sizes[2];

    char* ws = (char*)d_ws;
    int*            deg   = (int*)(ws);                       // 3.2 MB
    int*            rptr  = (int*)(ws + 3200000);             // 3.2 MB
    int*            bsum  = (int*)(ws + 6400000);             // 4 KB
    int*            boff  = (int*)(ws + 6404096);             // 4 KB
    int2*           pairs = (int2*)(ws + 6408192);            // 8 MB
    unsigned short* y     = (unsigned short*)(ws + 14408192); // 102.4 MB

    hipMemsetAsync(deg, 0, (size_t)RN * sizeof(int), stream);

    k_degree<<<(E + 255) / 256, 256, 0, stream>>>(rows, deg, E);
    k_bsum<<<NB_SCAN, 256, 0, stream>>>(deg, bsum);
    k_scan_mid<<<1, 1024, 0, stream>>>(bsum, boff);
    k_rowptr<<<NB_SCAN, 256, 0, stream>>>(deg, boff, rptr);
    k_sort<<<(E + 255) / 256, 256, 0, stream>>>(rows, cols, deg, rptr, pairs, E);
    k_gemm1<<<G1_BLOCKS, 512, 0, stream>>>(x, w, y);
    k_gather<<<(NNODES + 3) / 4, 256, 0, stream>>>(rptr, pairs, y, out);
}